// Round 6
// baseline (8312.253 us; speedup 1.0000x reference)
//
#include <hip/hip_runtime.h>
#include <hip/hip_bf16.h>

#define LSTEPS 256

typedef short  bf16x8_t  __attribute__((ext_vector_type(8)));
typedef float  f32x4_t   __attribute__((ext_vector_type(4)));
typedef unsigned short us4_t __attribute__((ext_vector_type(4)));

static __device__ __forceinline__ unsigned short f2bf(float f) {
  unsigned int u = __float_as_uint(f);
  unsigned int r = (u + 0x7fffu + ((u >> 16) & 1u)) >> 16;
  return (unsigned short)r;
}
static __device__ __forceinline__ float tanh_fast(float x) {
  float e = __expf(2.f * x);
  return 1.f - 2.f / (e + 1.f);
}

// ---------------- prep: Wcat [2048][4096] bf16 ----------------
__global__ __launch_bounds__(256) void prep_wc_kernel(
    const float* __restrict__ wcls, const float* __restrict__ wdist,
    unsigned short* __restrict__ Wcat)
{
  const int row = blockIdx.x;
  const float* src = nullptr;
  if (row < 1000) src = wcls + (size_t)row * 4096;
  else if (row >= 1024 && row < 2024) src = wdist + (size_t)(row - 1024) * 4096;
  unsigned short* dst = Wcat + (size_t)row * 4096;
  #pragma unroll 4
  for (int r = 0; r < 16; ++r) {
    const int c = r * 256 + threadIdx.x;
    dst[c] = src ? f2bf(src[c]) : (unsigned short)0;
  }
}

// ---------------- conv1d front end: U tiled [t][kg][row][8] bf16 ----------------
__global__ __launch_bounds__(256) void conv_kernel(
    const float* __restrict__ x, const float* __restrict__ w,
    const float* __restrict__ bias, unsigned short* __restrict__ U)
{
  __shared__ float wl[192][64];
  const int b  = blockIdx.x >> 4;
  const int tg = blockIdx.x & 15;
  const int tid = threadIdx.x;
  for (int i = tid; i < 64 * 192; i += 256)
    wl[i % 192][i / 192] = w[i];
  __syncthreads();
  const int wv = tid >> 6, p = tid & 63;
  const float* xb = x + (size_t)b * (3 * 8224);
  const float bp = bias[p];
  for (int tt = 0; tt < 4; ++tt) {
    const int t = tg * 16 + wv * 4 + tt;
    float acc = bp;
    const float* xw = xb + t * 32;
    #pragma unroll
    for (int c = 0; c < 3; ++c)
      #pragma unroll 8
      for (int k = 0; k < 64; ++k)
        acc += xw[c * 8224 + k] * wl[c * 64 + k][p];
    U[((size_t)t * 8 + (p >> 3)) * 1024 + (size_t)b * 8 + (p & 7)] = f2bf(acc);
  }
}

// ---------------- token broadcast into U[256], U[257] (tiled) ----------------
__global__ __launch_bounds__(256) void prep_tok_kernel(
    const float* __restrict__ cls, const float* __restrict__ dist,
    unsigned short* __restrict__ U)
{
  const int i = blockIdx.x * 256 + threadIdx.x;   // 16384 total
  const int s = i >> 13, rem = i & 8191;
  const int kg = rem >> 10, e = rem & 7;
  const float* tok = s ? dist : cls;
  U[(size_t)(256 + s) * 8192 + rem] = f2bf(tok[kg * 8 + e]);
}

// ---------------- persistent reservoir: producer-group sync, no global barrier -
// 256 WGs x 512 thr. cg = bid>>1 owns cols [cg*32,+32); bh = bid&1 owns batch
// rows [bh*64,+64). Wave w owns K-slice [w*512,+512): W chunks 0..13 in regs
// (wf[14][2]), chunks 14/15 + u-frags in LDS. 12 plain loads in flight (r5).
// SYNC (new): the global barrier is replaced by 16 producer-group counters
// (bh x 8 groups of 16 cg). Block release-adds 1 to cnt[bh][cg>>4] after its
// A(t+1) write; wave w acquire-waits cnt[bh][w] >= 16*t before reading A(t).
// A is TRIPLE buffered: a writer of A(s+1) has passed all 8 waits at 16*s =>
// every block finished step s-1 => no reader of A(s-2) exists => WAR-safe.
// Steps decouple (slack absorbed), release is staggered per group, bh halves
// fully independent. Release/acquire idiom identical to the proven barrier.
__global__ __launch_bounds__(512, 2) void reservoir_persistent(
    const float* __restrict__ wres,          // [4096][4096] f32
    const unsigned short* __restrict__ U,    // [258][8 kg][128][8] bf16 tiled
    const float* __restrict__ winp,          // [4096][64] f32
    unsigned short* __restrict__ A0, unsigned short* __restrict__ A1,
    unsigned short* __restrict__ A2,
    unsigned short* __restrict__ Hcls, unsigned short* __restrict__ Hdist,
    unsigned int* __restrict__ cnt)
{
  extern __shared__ char smem[];
  float* Pl = (float*)smem;                              // [8][64][33] f32 = 67584 B
  unsigned short* Wu = (unsigned short*)(smem + 67584);  // [2 ct][2 w][64][8] = 4096 B
  char* Wl2 = smem + 71680;                              // [8 w][4 frag][64 lane][16B] = 32768 B

  const int bid  = blockIdx.x;
  const int tid  = threadIdx.x;
  const int w    = tid >> 6;
  const int lane = tid & 63;
  const int q    = lane >> 4;
  const int r    = lane & 15;
  const int cg   = bid >> 1;
  const int bh   = bid & 1;
  const int nbase = cg * 32;
  const int l16  = lane * 16;

  // ---- prologue: wave's W K-slice -> regs (chunks 0..13) / LDS (14,15) ----
  bf16x8_t wf[14][2];
  #pragma unroll
  for (int kk = 0; kk < 16; ++kk)
    #pragma unroll
    for (int ct = 0; ct < 2; ++ct) {
      const float* src = wres + (size_t)(w * 512 + kk * 32 + q * 8) * 4096
                              + nbase + ct * 16 + r;
      bf16x8_t f;
      #pragma unroll
      for (int e = 0; e < 8; ++e) f[e] = (short)f2bf(src[(size_t)e * 4096]);
      if (kk < 14) wf[kk][ct] = f;
      else *(bf16x8_t*)(Wl2 + w * 4096 + ((kk - 14) * 2 + ct) * 1024 + l16) = f;
    }
  if (w < 2) {                               // u-part frags parked in LDS
    #pragma unroll
    for (int ct = 0; ct < 2; ++ct) {
      const float* src = winp + (size_t)(nbase + ct * 16 + r) * 64 + w * 32 + q * 8;
      bf16x8_t f;
      #pragma unroll
      for (int e = 0; e < 8; ++e) f[e] = (short)f2bf(src[e]);
      *(bf16x8_t*)(Wu + ((size_t)(ct * 2 + w) * 64 + lane) * 8) = f;
    }
  }

  // lane's A base in bf16x8 (16B) units: kg = w*64+q (+4/chunk), row = bh*64+r
  const int au = (w * 64 + q) * 128 + bh * 64 + r;
  const int uu = (w * 4 + q) * 128 + bh * 64 + r;   // U slab unit idx (waves 0/1)

  const int erow = tid >> 3;                 // reduce-phase mapping
  const int cb   = (tid & 7) * 4;
  const size_t awoff = ((size_t)(cg * 4 + (cb >> 3)) * 128 + bh * 64 + erow) * 8 + (cb & 7);
  const size_t hoff  = (size_t)(bh * 64 + erow) * 4096 + nbase + cb;

  volatile unsigned int* mycnt = &cnt[(bh * 8 + w) * 32];
  unsigned int* addcnt = &cnt[(bh * 8 + (cg >> 4)) * 32];

#define LD(BUF, KK)                                                          \
  { BUF[0] = Ab[au + (KK) * 512];      BUF[1] = Ab[au + (KK) * 512 + 16];    \
    BUF[2] = Ab[au + (KK) * 512 + 32]; BUF[3] = Ab[au + (KK) * 512 + 48]; }

#define MMc(BUF, KK)                                                         \
  { acc[0][0] = __builtin_amdgcn_mfma_f32_16x16x32_bf16(BUF[0], wf[KK][0], acc[0][0], 0, 0, 0); \
    acc[0][1] = __builtin_amdgcn_mfma_f32_16x16x32_bf16(BUF[0], wf[KK][1], acc[0][1], 0, 0, 0); \
    acc[1][0] = __builtin_amdgcn_mfma_f32_16x16x32_bf16(BUF[1], wf[KK][0], acc[1][0], 0, 0, 0); \
    acc[1][1] = __builtin_amdgcn_mfma_f32_16x16x32_bf16(BUF[1], wf[KK][1], acc[1][1], 0, 0, 0); \
    acc[2][0] = __builtin_amdgcn_mfma_f32_16x16x32_bf16(BUF[2], wf[KK][0], acc[2][0], 0, 0, 0); \
    acc[2][1] = __builtin_amdgcn_mfma_f32_16x16x32_bf16(BUF[2], wf[KK][1], acc[2][1], 0, 0, 0); \
    acc[3][0] = __builtin_amdgcn_mfma_f32_16x16x32_bf16(BUF[3], wf[KK][0], acc[3][0], 0, 0, 0); \
    acc[3][1] = __builtin_amdgcn_mfma_f32_16x16x32_bf16(BUF[3], wf[KK][1], acc[3][1], 0, 0, 0); }

#define MMW(BUF, W0, W1)                                                     \
  { acc[0][0] = __builtin_amdgcn_mfma_f32_16x16x32_bf16(BUF[0], W0, acc[0][0], 0, 0, 0); \
    acc[0][1] = __builtin_amdgcn_mfma_f32_16x16x32_bf16(BUF[0], W1, acc[0][1], 0, 0, 0); \
    acc[1][0] = __builtin_amdgcn_mfma_f32_16x16x32_bf16(BUF[1], W0, acc[1][0], 0, 0, 0); \
    acc[1][1] = __builtin_amdgcn_mfma_f32_16x16x32_bf16(BUF[1], W1, acc[1][1], 0, 0, 0); \
    acc[2][0] = __builtin_amdgcn_mfma_f32_16x16x32_bf16(BUF[2], W0, acc[2][0], 0, 0, 0); \
    acc[2][1] = __builtin_amdgcn_mfma_f32_16x16x32_bf16(BUF[2], W1, acc[2][1], 0, 0, 0); \
    acc[3][0] = __builtin_amdgcn_mfma_f32_16x16x32_bf16(BUF[3], W0, acc[3][0], 0, 0, 0); \
    acc[3][1] = __builtin_amdgcn_mfma_f32_16x16x32_bf16(BUF[3], W1, acc[3][1], 0, 0, 0); }

  #pragma unroll 1
  for (int t = 0; t < LSTEPS + 2; ++t) {
    const int tr  = (t <= LSTEPS) ? (t % 3) : (LSTEPS % 3);
    const int tw  = (t + 1) % 3;
    const unsigned short* Arp = (tr == 0) ? A0 : (tr == 1) ? A1 : A2;
    unsigned short*       Awp = (tw == 0) ? A0 : (tw == 1) ? A1 : A2;
    const bf16x8_t* __restrict__ Ab = (const bf16x8_t*)Arp;
    const bf16x8_t* __restrict__ Ub = (const bf16x8_t*)(U + (size_t)t * 8192);

    // ---- wait for this wave's producer group: A(t) complete ----
    if (t > 0) {
      const unsigned int thr = 16u * (unsigned int)((t < LSTEPS) ? t : LSTEPS);
      if (lane == 0) {
        while (__hip_atomic_load(mycnt, __ATOMIC_RELAXED,
                                 __HIP_MEMORY_SCOPE_SYSTEM) < thr)
          __builtin_amdgcn_s_sleep(1);
      }
      __builtin_amdgcn_fence(__ATOMIC_ACQUIRE, "agent");
      __builtin_amdgcn_sched_barrier(0);
    }

    f32x4_t acc[4][2];
    #pragma unroll
    for (int m = 0; m < 4; ++m) {
      acc[m][0] = (f32x4_t){0.f, 0.f, 0.f, 0.f};
      acc[m][1] = (f32x4_t){0.f, 0.f, 0.f, 0.f};
    }

    bf16x8_t b0[4], b1[4], b2[4];
    LD(b0, 0); LD(b1, 1); LD(b2, 2);         // 12 loads in flight

    MMc(b0, 0);  LD(b0, 3);
    MMc(b1, 1);  LD(b1, 4);
    MMc(b2, 2);  LD(b2, 5);
    MMc(b0, 3);  LD(b0, 6);
    MMc(b1, 4);  LD(b1, 7);
    MMc(b2, 5);  LD(b2, 8);
    MMc(b0, 6);  LD(b0, 9);
    MMc(b1, 7);  LD(b1, 10);
    MMc(b2, 8);  LD(b2, 11);
    MMc(b0, 9);  LD(b0, 12);
    MMc(b1, 10); LD(b1, 13);
    MMc(b2, 11); LD(b2, 14);
    MMc(b0, 12); LD(b0, 15);

    bf16x8_t bu[4];
    if (w < 2) {                             // U slab loads (static, no dep)
      bu[0] = Ub[uu];      bu[1] = Ub[uu + 16];
      bu[2] = Ub[uu + 32]; bu[3] = Ub[uu + 48];
    }
    MMc(b1, 13);
    {                                        // chunks 14/15: W frags from LDS
      const char* wl = Wl2 + w * 4096 + l16;
      bf16x8_t w14a = *(const bf16x8_t*)(wl);
      bf16x8_t w14b = *(const bf16x8_t*)(wl + 1024);
      bf16x8_t w15a = *(const bf16x8_t*)(wl + 2048);
      bf16x8_t w15b = *(const bf16x8_t*)(wl + 3072);
      MMW(b2, w14a, w14b);
      MMW(b0, w15a, w15b);
    }
    if (w < 2) {                             // u half-window
      bf16x8_t wu0 = *(const bf16x8_t*)(Wu + ((size_t)(0 * 2 + w) * 64 + lane) * 8);
      bf16x8_t wu1 = *(const bf16x8_t*)(Wu + ((size_t)(1 * 2 + w) * 64 + lane) * 8);
      MMW(bu, wu0, wu1);
    }

    // ---- cross-wave K reduction through LDS ----
    __syncthreads();
    #pragma unroll
    for (int rt = 0; rt < 4; ++rt)
      #pragma unroll
      for (int ct = 0; ct < 2; ++ct)
        #pragma unroll
        for (int i = 0; i < 4; ++i)
          Pl[(w * 64 + rt * 16 + q * 4 + i) * 33 + ct * 16 + r] = acc[rt][ct][i];
    __syncthreads();

    {
      float s0 = 0.f, s1 = 0.f, s2 = 0.f, s3 = 0.f;
      #pragma unroll
      for (int wv = 0; wv < 8; ++wv) {
        const float* p = Pl + (wv * 64 + erow) * 33 + cb;
        s0 += p[0]; s1 += p[1]; s2 += p[2]; s3 += p[3];
      }
      us4_t o;
      o[0] = f2bf(tanh_fast(s0));
      o[1] = f2bf(tanh_fast(s1));
      o[2] = f2bf(tanh_fast(s2));
      o[3] = f2bf(tanh_fast(s3));
      if (t < LSTEPS) {
        *(us4_t*)(Awp + awoff) = o;          // tiled A cell, 8B store
      } else {
        unsigned short* H = (t == LSTEPS) ? Hcls : Hdist;
        *(us4_t*)(H + hoff) = o;             // row-major H, 8B store
      }
    }

    // ---- signal: this block's A(t+1) cells are written ----
    __syncthreads();                         // drains all 512 threads' stores
    if (tid == 0 && t < LSTEPS)
      __hip_atomic_fetch_add(addcnt, 1u, __ATOMIC_RELEASE,
                             __HIP_MEMORY_SCOPE_AGENT);
  }
#undef LD
#undef MMc
#undef MMW
}

// ---------------- classifier K-split GEMM (f32 partials) ----------
__global__ __launch_bounds__(256) void gemm_ksplit(
    const unsigned short* __restrict__ A0, const unsigned short* __restrict__ A1,
    int nsplit, int lda,
    const unsigned short* __restrict__ BT, int ldb,
    float* __restrict__ P, int ntiles, int klen, int klen_last)
{
  __shared__ unsigned short sA[128 * 64];
  __shared__ unsigned short sB[128 * 64];

  const int bid = blockIdx.x;
  const int nt = bid % ntiles;
  const int s  = bid / ntiles;
  const unsigned short* __restrict__ A = (nt < nsplit) ? A0 : A1;
  const int kb0 = s * klen;
  const int KL  = (s == 7) ? klen_last : klen;
  const int nbase = nt * 128;

  const int tid = threadIdx.x;
  const int w = tid >> 6;
  const int lane = tid & 63;
  const int wr = w >> 1, wc = w & 1;

  f32x4_t acc[4][4];
  #pragma unroll
  for (int m = 0; m < 4; ++m)
    #pragma unroll
    for (int n = 0; n < 4; ++n)
      acc[m][n] = (f32x4_t){0.f, 0.f, 0.f, 0.f};

  const int srow = lane >> 3;
  const int slotL = (lane & 7) ^ srow;

  for (int kb = 0; kb < KL; kb += 64) {
    const int kcol = kb0 + kb + slotL * 8;
    #pragma unroll
    for (int qq = 0; qq < 4; ++qq) {
      const int row = 32 * w + 8 * qq + srow;
      __builtin_amdgcn_global_load_lds(
          (const __attribute__((address_space(1))) void*)(A + (size_t)row * lda + kcol),
          (__attribute__((address_space(3))) void*)(&sA[(32 * w + 8 * qq) * 64]),
          16, 0, 0);
      __builtin_amdgcn_global_load_lds(
          (const __attribute__((address_space(1))) void*)(BT + (size_t)(nbase + row) * ldb + kcol),
          (__attribute__((address_space(3))) void*)(&sB[(32 * w + 8 * qq) * 64]),
          16, 0, 0);
    }
    __syncthreads();

    #pragma unroll
    for (int ksub = 0; ksub < 2; ++ksub) {
      bf16x8_t af[4], bfr[4];
      #pragma unroll
      for (int m = 0; m < 4; ++m) {
        const int row = 64 * wr + 16 * m + (lane & 15);
        const int kslot = (ksub * 4 + (lane >> 4)) ^ (row & 7);
        af[m] = *(const bf16x8_t*)(&sA[row * 64 + kslot * 8]);
      }
      #pragma unroll
      for (int n = 0; n < 4; ++n) {
        const int row = 64 * wc + 16 * n + (lane & 15);
        const int kslot = (ksub * 4 + (lane >> 4)) ^ (row & 7);
        bfr[n] = *(const bf16x8_t*)(&sB[row * 64 + kslot * 8]);
      }
      #pragma unroll
      for (int m = 0; m < 4; ++m)
        #pragma unroll
        for (int n = 0; n < 4; ++n)
          acc[m][n] = __builtin_amdgcn_mfma_f32_16x16x32_bf16(af[m], bfr[n], acc[m][n], 0, 0, 0);
    }
    __syncthreads();
  }

  float* __restrict__ Pp = P + (size_t)s * (128 * 4096);
  #pragma unroll
  for (int m = 0; m < 4; ++m) {
    const int rbase = 64 * wr + 16 * m + ((lane >> 4) << 2);
    #pragma unroll
    for (int n = 0; n < 4; ++n) {
      const int col = nbase + 64 * wc + 16 * n + (lane & 15);
      #pragma unroll
      for (int r = 0; r < 4; ++r)
        Pp[(size_t)(rbase + r) * 4096 + col] = acc[m][n][r];
    }
  }
}

// ---------------- reduce 8 f32 partials -> fp32 logits [128][2048] ------------
__global__ __launch_bounds__(256) void reduce_linear_kernel(
    const float* __restrict__ P, float* __restrict__ logits)
{
  const int e = blockIdx.x * 1024 + threadIdx.x * 4;
  const int b = e >> 11;
  const int n = e & 2047;
  const size_t off = (size_t)b * 4096 + n;
  float4 sum = *(const float4*)(&P[off]);
  #pragma unroll
  for (int s = 1; s < 8; ++s) {
    float4 v = *(const float4*)(&P[(size_t)s * 524288 + off]);
    sum.x += v.x; sum.y += v.y; sum.z += v.z; sum.w += v.w;
  }
  *(float4*)(&logits[e]) = sum;
}

// ---------------- bias + average + log_softmax ----------------
__global__ __launch_bounds__(256) void logsoftmax_kernel(
    const float* __restrict__ logits, const float* __restrict__ bcls,
    const float* __restrict__ bdist, float* __restrict__ out)
{
  __shared__ float v[1000];
  __shared__ float red[256];
  const int b = blockIdx.x;
  const int tid = threadIdx.x;
  float lmax = -1e30f;
  for (int n = tid; n < 1000; n += 256) {
    float val = 0.5f * (logits[(size_t)b * 2048 + n] + bcls[n]
                      + logits[(size_t)b * 2048 + 1024 + n] + bdist[n]);
    v[n] = val;
    lmax = fmaxf(lmax, val);
  }
  red[tid] = lmax; __syncthreads();
  for (int st = 128; st > 0; st >>= 1) {
    if (tid < st) red[tid] = fmaxf(red[tid], red[tid + st]);
    __syncthreads();
  }
  const float mx = red[0];
  __syncthreads();
  float lsum = 0.f;
  for (int n = tid; n < 1000; n += 256) lsum += expf(v[n] - mx);
  red[tid] = lsum; __syncthreads();
  for (int st = 128; st > 0; st >>= 1) {
    if (tid < st) red[tid] += red[tid + st];
    __syncthreads();
  }
  const float lse = logf(red[0]) + mx;
  for (int n = tid; n < 1000; n += 256) out[(size_t)b * 1000 + n] = v[n] - lse;
}

// ---------------- host ----------------
extern "C" void kernel_launch(void* const* d_in, const int* in_sizes, int n_in,
                              void* d_out, int out_size, void* d_ws, size_t ws_size,
                              hipStream_t stream)
{
  (void)in_sizes; (void)n_in; (void)out_size; (void)ws_size;
  const float* x      = (const float*)d_in[0];
  const float* convw  = (const float*)d_in[1];
  const float* convb  = (const float*)d_in[2];
  const float* wres   = (const float*)d_in[3];
  const float* winp   = (const float*)d_in[4];
  const float* clstok = (const float*)d_in[5];
  const float* dsttok = (const float*)d_in[6];
  const float* wcls   = (const float*)d_in[7];
  const float* bcls   = (const float*)d_in[8];
  const float* wdist  = (const float*)d_in[9];
  const float* bdist  = (const float*)d_in[10];
  float* out = (float*)d_out;

  char* ws = (char*)d_ws;
  unsigned short* U     = (unsigned short*)(ws + 0);           //  4,227,072 (258 steps, tiled)
  unsigned short* A0    = (unsigned short*)(ws + 4227072);     //  1,048,576 (tiled)
  unsigned short* A1    = (unsigned short*)(ws + 5275648);     //  1,048,576 (tiled)
  unsigned short* Hcls  = (unsigned short*)(ws + 6324224);     //  1,048,576 (row-major)
  unsigned short* Hdist = (unsigned short*)(ws + 7372800);     //  1,048,576 (row-major)
  unsigned short* Wcat  = (unsigned short*)(ws + 8421376);     // 16,777,216
  float*          P     = (float*)(ws + 25198592);             // 16,777,216
  float*          logit = (float*)(ws + 41975808);             //  1,048,576
  unsigned int*   lcnt  = (unsigned int*)(ws + 43024384);      //  4 KB (producer counters)
  unsigned short* A2    = (unsigned short*)(ws + 25198592);    //  aliases P head (timeline-disjoint)

  hipFuncSetAttribute((const void*)reservoir_persistent,
                      hipFuncAttributeMaxDynamicSharedMemorySize, 104448);

  hipMemsetAsync(A0, 0, 2 * 1048576, stream);                  // A0 + A1 (h0 = 0)
  hipMemsetAsync(lcnt, 0, 4096, stream);                       // producer counters

  prep_wc_kernel<<<2048, 256, 0, stream>>>(wcls, wdist, Wcat);
  conv_kernel<<<2048, 256, 0, stream>>>(x, convw, convb, U);
  prep_tok_kernel<<<64, 256, 0, stream>>>(clstok, dsttok, U);

  reservoir_persistent<<<256, 512, 104448, stream>>>(
      wres, U, winp, A0, A1, A2, Hcls, Hdist, lcnt);

  gemm_ksplit<<<128, 256, 0, stream>>>(Hcls, Hdist, 8, 4096, Wcat, 4096, P, 16, 512, 512);
  reduce_linear_kernel<<<256, 256, 0, stream>>>(P, logit);
  logsoftmax_kernel<<<128, 256, 0, stream>>>(logit, bcls, bdist, out);
}

// Round 7
// 4975.948 us; speedup vs baseline: 1.6705x; 1.6705x over previous
//
#include <hip/hip_runtime.h>
#include <hip/hip_bf16.h>

#define LSTEPS 256

typedef short  bf16x8_t  __attribute__((ext_vector_type(8)));
typedef float  f32x4_t   __attribute__((ext_vector_type(4)));
typedef unsigned short us4_t __attribute__((ext_vector_type(4)));

static __device__ __forceinline__ unsigned short f2bf(float f) {
  unsigned int u = __float_as_uint(f);
  unsigned int r = (u + 0x7fffu + ((u >> 16) & 1u)) >> 16;
  return (unsigned short)r;
}
static __device__ __forceinline__ float tanh_fast(float x) {
  float e = __expf(2.f * x);
  return 1.f - 2.f / (e + 1.f);
}

// ---------------- prep: Wcat [2048][4096] bf16 ----------------
__global__ __launch_bounds__(256) void prep_wc_kernel(
    const float* __restrict__ wcls, const float* __restrict__ wdist,
    unsigned short* __restrict__ Wcat)
{
  const int row = blockIdx.x;
  const float* src = nullptr;
  if (row < 1000) src = wcls + (size_t)row * 4096;
  else if (row >= 1024 && row < 2024) src = wdist + (size_t)(row - 1024) * 4096;
  unsigned short* dst = Wcat + (size_t)row * 4096;
  #pragma unroll 4
  for (int r = 0; r < 16; ++r) {
    const int c = r * 256 + threadIdx.x;
    dst[c] = src ? f2bf(src[c]) : (unsigned short)0;
  }
}

// ---------------- conv1d front end: U tiled [t][kg][row][8] bf16 ----------------
__global__ __launch_bounds__(256) void conv_kernel(
    const float* __restrict__ x, const float* __restrict__ w,
    const float* __restrict__ bias, unsigned short* __restrict__ U)
{
  __shared__ float wl[192][64];
  const int b  = blockIdx.x >> 4;
  const int tg = blockIdx.x & 15;
  const int tid = threadIdx.x;
  for (int i = tid; i < 64 * 192; i += 256)
    wl[i % 192][i / 192] = w[i];
  __syncthreads();
  const int wv = tid >> 6, p = tid & 63;
  const float* xb = x + (size_t)b * (3 * 8224);
  const float bp = bias[p];
  for (int tt = 0; tt < 4; ++tt) {
    const int t = tg * 16 + wv * 4 + tt;
    float acc = bp;
    const float* xw = xb + t * 32;
    #pragma unroll
    for (int c = 0; c < 3; ++c)
      #pragma unroll 8
      for (int k = 0; k < 64; ++k)
        acc += xw[c * 8224 + k] * wl[c * 64 + k][p];
    U[((size_t)t * 8 + (p >> 3)) * 1024 + (size_t)b * 8 + (p & 7)] = f2bf(acc);
  }
}

// ---------------- token broadcast into U[256], U[257] (tiled) ----------------
__global__ __launch_bounds__(256) void prep_tok_kernel(
    const float* __restrict__ cls, const float* __restrict__ dist,
    unsigned short* __restrict__ U)
{
  const int i = blockIdx.x * 256 + threadIdx.x;   // 16384 total
  const int s = i >> 13, rem = i & 8191;
  const int kg = rem >> 10, e = rem & 7;
  const float* tok = s ? dist : cls;
  U[(size_t)(256 + s) * 8192 + rem] = f2bf(tok[kg * 8 + e]);
}

// ---------------- persistent reservoir: producer-group sync (1 poller/block) --
// 256 WGs x 512 thr. XCD-aware remap: xcd = bid&7 (dispatch round-robin),
// XCDs 0-3 -> bh0, 4-7 -> bh1; cg = (xcd&3)*32 + bid>>3. Each bh half is
// produced AND consumed within one 4-XCD group (halves cross-fabric traffic).
// Wave w owns K-slice [w*512,+512): W chunks 0..13 in regs, 14/15 + u in LDS.
// 12 plain loads in flight (r5 pipeline, compiler-tracked waitcnts).
// SYNC: 16 producer-group counters (bh x 8 groups of 16 cg; each group's
// blocks live on ONE XCD -> adds stay L2-local). tid==0 ONLY polls the 8
// counters of its bh with s_sleep(8) backoff (256 pollers ~ r5's proven
// traffic; r6's 2048-spinner meltdown fixed), acquire-load, __syncthreads.
// Triple-buffered A: a block at step t confirmed all bh-blocks completed step
// t-1 => no reader of A(t-2) exists => WAR-safe. Release-add after the
// post-store __syncthreads (proven r0 idiom).
__global__ __launch_bounds__(512, 2) void reservoir_persistent(
    const float* __restrict__ wres,          // [4096][4096] f32
    const unsigned short* __restrict__ U,    // [258][8 kg][128][8] bf16 tiled
    const float* __restrict__ winp,          // [4096][64] f32
    unsigned short* __restrict__ A0, unsigned short* __restrict__ A1,
    unsigned short* __restrict__ A2,
    unsigned short* __restrict__ Hcls, unsigned short* __restrict__ Hdist,
    unsigned int* __restrict__ cnt)
{
  extern __shared__ char smem[];
  float* Pl = (float*)smem;                              // [8][64][36] f32 = 73728 B
  unsigned short* Wu = (unsigned short*)(smem + 73728);  // [2 ct][2 w][64][8] = 4096 B
  char* Wl2 = smem + 77824;                              // [8 w][4 frag][64 lane][16B] = 32768 B

  const int bid  = blockIdx.x;
  const int tid  = threadIdx.x;
  const int w    = tid >> 6;
  const int lane = tid & 63;
  const int q    = lane >> 4;
  const int r    = lane & 15;
  const int xcd  = bid & 7;
  const int bh   = xcd >> 2;
  const int cg   = (xcd & 3) * 32 + (bid >> 3);
  const int nbase = cg * 32;
  const int l16  = lane * 16;

  // ---- prologue: wave's W K-slice -> regs (chunks 0..13) / LDS (14,15) ----
  bf16x8_t wf[14][2];
  #pragma unroll
  for (int kk = 0; kk < 16; ++kk)
    #pragma unroll
    for (int ct = 0; ct < 2; ++ct) {
      const float* src = wres + (size_t)(w * 512 + kk * 32 + q * 8) * 4096
                              + nbase + ct * 16 + r;
      bf16x8_t f;
      #pragma unroll
      for (int e = 0; e < 8; ++e) f[e] = (short)f2bf(src[(size_t)e * 4096]);
      if (kk < 14) wf[kk][ct] = f;
      else *(bf16x8_t*)(Wl2 + w * 4096 + ((kk - 14) * 2 + ct) * 1024 + l16) = f;
    }
  if (w < 2) {                               // u-part frags parked in LDS
    #pragma unroll
    for (int ct = 0; ct < 2; ++ct) {
      const float* src = winp + (size_t)(nbase + ct * 16 + r) * 64 + w * 32 + q * 8;
      bf16x8_t f;
      #pragma unroll
      for (int e = 0; e < 8; ++e) f[e] = (short)f2bf(src[e]);
      *(bf16x8_t*)(Wu + ((size_t)(ct * 2 + w) * 64 + lane) * 8) = f;
    }
  }

  // lane's A base in bf16x8 (16B) units: kg = w*64+q (+4/chunk), row = bh*64+r
  const int au = (w * 64 + q) * 128 + bh * 64 + r;
  const int uu = (w * 4 + q) * 128 + bh * 64 + r;   // U slab unit idx (waves 0/1)

  const int erow = tid >> 3;                 // reduce-phase mapping
  const int cb   = (tid & 7) * 4;
  const size_t awoff = ((size_t)(cg * 4 + (cb >> 3)) * 128 + bh * 64 + erow) * 8 + (cb & 7);
  const size_t hoff  = (size_t)(bh * 64 + erow) * 4096 + nbase + cb;

  unsigned int* grpcnt = &cnt[(bh * 8 + (cg >> 4)) * 32];

#define LD(BUF, KK)                                                          \
  { BUF[0] = Ab[au + (KK) * 512];      BUF[1] = Ab[au + (KK) * 512 + 16];    \
    BUF[2] = Ab[au + (KK) * 512 + 32]; BUF[3] = Ab[au + (KK) * 512 + 48]; }

#define MMc(BUF, KK)                                                         \
  { acc[0][0] = __builtin_amdgcn_mfma_f32_16x16x32_bf16(BUF[0], wf[KK][0], acc[0][0], 0, 0, 0); \
    acc[0][1] = __builtin_amdgcn_mfma_f32_16x16x32_bf16(BUF[0], wf[KK][1], acc[0][1], 0, 0, 0); \
    acc[1][0] = __builtin_amdgcn_mfma_f32_16x16x32_bf16(BUF[1], wf[KK][0], acc[1][0], 0, 0, 0); \
    acc[1][1] = __builtin_amdgcn_mfma_f32_16x16x32_bf16(BUF[1], wf[KK][1], acc[1][1], 0, 0, 0); \
    acc[2][0] = __builtin_amdgcn_mfma_f32_16x16x32_bf16(BUF[2], wf[KK][0], acc[2][0], 0, 0, 0); \
    acc[2][1] = __builtin_amdgcn_mfma_f32_16x16x32_bf16(BUF[2], wf[KK][1], acc[2][1], 0, 0, 0); \
    acc[3][0] = __builtin_amdgcn_mfma_f32_16x16x32_bf16(BUF[3], wf[KK][0], acc[3][0], 0, 0, 0); \
    acc[3][1] = __builtin_amdgcn_mfma_f32_16x16x32_bf16(BUF[3], wf[KK][1], acc[3][1], 0, 0, 0); }

#define MMW(BUF, W0, W1)                                                     \
  { acc[0][0] = __builtin_amdgcn_mfma_f32_16x16x32_bf16(BUF[0], W0, acc[0][0], 0, 0, 0); \
    acc[0][1] = __builtin_amdgcn_mfma_f32_16x16x32_bf16(BUF[0], W1, acc[0][1], 0, 0, 0); \
    acc[1][0] = __builtin_amdgcn_mfma_f32_16x16x32_bf16(BUF[1], W0, acc[1][0], 0, 0, 0); \
    acc[1][1] = __builtin_amdgcn_mfma_f32_16x16x32_bf16(BUF[1], W1, acc[1][1], 0, 0, 0); \
    acc[2][0] = __builtin_amdgcn_mfma_f32_16x16x32_bf16(BUF[2], W0, acc[2][0], 0, 0, 0); \
    acc[2][1] = __builtin_amdgcn_mfma_f32_16x16x32_bf16(BUF[2], W1, acc[2][1], 0, 0, 0); \
    acc[3][0] = __builtin_amdgcn_mfma_f32_16x16x32_bf16(BUF[3], W0, acc[3][0], 0, 0, 0); \
    acc[3][1] = __builtin_amdgcn_mfma_f32_16x16x32_bf16(BUF[3], W1, acc[3][1], 0, 0, 0); }

  #pragma unroll 1
  for (int t = 0; t < LSTEPS + 2; ++t) {
    const int tr  = (t <= LSTEPS) ? (t % 3) : (LSTEPS % 3);
    const int tw  = (t + 1) % 3;
    const unsigned short* Arp = (tr == 0) ? A0 : (tr == 1) ? A1 : A2;
    unsigned short*       Awp = (tw == 0) ? A0 : (tw == 1) ? A1 : A2;
    const bf16x8_t* __restrict__ Ab = (const bf16x8_t*)Arp;
    const bf16x8_t* __restrict__ Ub = (const bf16x8_t*)(U + (size_t)t * 8192);

    bf16x8_t bu[4];
    if (w < 2) {                             // U slab prefetch (static, no dep)
      bu[0] = Ub[uu];      bu[1] = Ub[uu + 16];
      bu[2] = Ub[uu + 32]; bu[3] = Ub[uu + 48];
    }

    // ---- wait: all 8 producer groups of this bh have completed A(t) ----
    if (t > 0) {
      const unsigned int thr = 16u * (unsigned int)((t < LSTEPS) ? t : LSTEPS);
      if (tid == 0) {
        #pragma unroll 1
        for (int gi = 0; gi < 8; ++gi) {
          const int g = (gi + (cg >> 4)) & 7;
          while (__hip_atomic_load(&cnt[(bh * 8 + g) * 32], __ATOMIC_RELAXED,
                                   __HIP_MEMORY_SCOPE_SYSTEM) < thr)
            __builtin_amdgcn_s_sleep(8);
        }
        (void)__hip_atomic_load(&cnt[bh * 8 * 32], __ATOMIC_ACQUIRE,
                                __HIP_MEMORY_SCOPE_AGENT);
      }
    }
    __syncthreads();

    f32x4_t acc[4][2];
    #pragma unroll
    for (int m = 0; m < 4; ++m) {
      acc[m][0] = (f32x4_t){0.f, 0.f, 0.f, 0.f};
      acc[m][1] = (f32x4_t){0.f, 0.f, 0.f, 0.f};
    }

    bf16x8_t b0[4], b1[4], b2[4];
    LD(b0, 0); LD(b1, 1); LD(b2, 2);         // 12 loads in flight

    MMc(b0, 0);  LD(b0, 3);
    MMc(b1, 1);  LD(b1, 4);
    MMc(b2, 2);  LD(b2, 5);
    MMc(b0, 3);  LD(b0, 6);
    MMc(b1, 4);  LD(b1, 7);
    MMc(b2, 5);  LD(b2, 8);
    MMc(b0, 6);  LD(b0, 9);
    MMc(b1, 7);  LD(b1, 10);
    MMc(b2, 8);  LD(b2, 11);
    MMc(b0, 9);  LD(b0, 12);
    MMc(b1, 10); LD(b1, 13);
    MMc(b2, 11); LD(b2, 14);
    MMc(b0, 12); LD(b0, 15);
    MMc(b1, 13);
    {                                        // chunks 14/15: W frags from LDS
      const char* wl = Wl2 + w * 4096 + l16;
      bf16x8_t w14a = *(const bf16x8_t*)(wl);
      bf16x8_t w14b = *(const bf16x8_t*)(wl + 1024);
      bf16x8_t w15a = *(const bf16x8_t*)(wl + 2048);
      bf16x8_t w15b = *(const bf16x8_t*)(wl + 3072);
      MMW(b2, w14a, w14b);
      MMW(b0, w15a, w15b);
    }
    if (w < 2) {                             // u half-window
      bf16x8_t wu0 = *(const bf16x8_t*)(Wu + ((size_t)(0 * 2 + w) * 64 + lane) * 8);
      bf16x8_t wu1 = *(const bf16x8_t*)(Wu + ((size_t)(1 * 2 + w) * 64 + lane) * 8);
      MMW(bu, wu0, wu1);
    }

    // ---- cross-wave K reduction through LDS (stride 36: f4-aligned reads) ----
    #pragma unroll
    for (int rt = 0; rt < 4; ++rt)
      #pragma unroll
      for (int ct = 0; ct < 2; ++ct)
        #pragma unroll
        for (int i = 0; i < 4; ++i)
          Pl[(w * 64 + rt * 16 + q * 4 + i) * 36 + ct * 16 + r] = acc[rt][ct][i];
    __syncthreads();

    {
      float s0 = 0.f, s1 = 0.f, s2 = 0.f, s3 = 0.f;
      #pragma unroll
      for (int wv = 0; wv < 8; ++wv) {
        const f32x4_t vv = *(const f32x4_t*)(Pl + (wv * 64 + erow) * 36 + cb);
        s0 += vv[0]; s1 += vv[1]; s2 += vv[2]; s3 += vv[3];
      }
      us4_t o;
      o[0] = f2bf(tanh_fast(s0));
      o[1] = f2bf(tanh_fast(s1));
      o[2] = f2bf(tanh_fast(s2));
      o[3] = f2bf(tanh_fast(s3));
      if (t < LSTEPS) {
        *(us4_t*)(Awp + awoff) = o;          // tiled A cell, 8B store
      } else {
        unsigned short* H = (t == LSTEPS) ? Hcls : Hdist;
        *(us4_t*)(H + hoff) = o;             // row-major H, 8B store
      }
    }

    // ---- signal: this block's A(t+1) cells are written ----
    __syncthreads();                         // drains all 512 threads' stores
    if (tid == 0 && t < LSTEPS)
      __hip_atomic_fetch_add(grpcnt, 1u, __ATOMIC_RELEASE,
                             __HIP_MEMORY_SCOPE_AGENT);
  }
#undef LD
#undef MMc
#undef MMW
}

// ---------------- classifier K-split GEMM (f32 partials) ----------
__global__ __launch_bounds__(256) void gemm_ksplit(
    const unsigned short* __restrict__ A0, const unsigned short* __restrict__ A1,
    int nsplit, int lda,
    const unsigned short* __restrict__ BT, int ldb,
    float* __restrict__ P, int ntiles, int klen, int klen_last)
{
  __shared__ unsigned short sA[128 * 64];
  __shared__ unsigned short sB[128 * 64];

  const int bid = blockIdx.x;
  const int nt = bid % ntiles;
  const int s  = bid / ntiles;
  const unsigned short* __restrict__ A = (nt < nsplit) ? A0 : A1;
  const int kb0 = s * klen;
  const int KL  = (s == 7) ? klen_last : klen;
  const int nbase = nt * 128;

  const int tid = threadIdx.x;
  const int w = tid >> 6;
  const int lane = tid & 63;
  const int wr = w >> 1, wc = w & 1;

  f32x4_t acc[4][4];
  #pragma unroll
  for (int m = 0; m < 4; ++m)
    #pragma unroll
    for (int n = 0; n < 4; ++n)
      acc[m][n] = (f32x4_t){0.f, 0.f, 0.f, 0.f};

  const int srow = lane >> 3;
  const int slotL = (lane & 7) ^ srow;

  for (int kb = 0; kb < KL; kb += 64) {
    const int kcol = kb0 + kb + slotL * 8;
    #pragma unroll
    for (int qq = 0; qq < 4; ++qq) {
      const int row = 32 * w + 8 * qq + srow;
      __builtin_amdgcn_global_load_lds(
          (const __attribute__((address_space(1))) void*)(A + (size_t)row * lda + kcol),
          (__attribute__((address_space(3))) void*)(&sA[(32 * w + 8 * qq) * 64]),
          16, 0, 0);
      __builtin_amdgcn_global_load_lds(
          (const __attribute__((address_space(1))) void*)(BT + (size_t)(nbase + row) * ldb + kcol),
          (__attribute__((address_space(3))) void*)(&sB[(32 * w + 8 * qq) * 64]),
          16, 0, 0);
    }
    __syncthreads();

    #pragma unroll
    for (int ksub = 0; ksub < 2; ++ksub) {
      bf16x8_t af[4], bfr[4];
      #pragma unroll
      for (int m = 0; m < 4; ++m) {
        const int row = 64 * wr + 16 * m + (lane & 15);
        const int kslot = (ksub * 4 + (lane >> 4)) ^ (row & 7);
        af[m] = *(const bf16x8_t*)(&sA[row * 64 + kslot * 8]);
      }
      #pragma unroll
      for (int n = 0; n < 4; ++n) {
        const int row = 64 * wc + 16 * n + (lane & 15);
        const int kslot = (ksub * 4 + (lane >> 4)) ^ (row & 7);
        bfr[n] = *(const bf16x8_t*)(&sB[row * 64 + kslot * 8]);
      }
      #pragma unroll
      for (int m = 0; m < 4; ++m)
        #pragma unroll
        for (int n = 0; n < 4; ++n)
          acc[m][n] = __builtin_amdgcn_mfma_f32_16x16x32_bf16(af[m], bfr[n], acc[m][n], 0, 0, 0);
    }
    __syncthreads();
  }

  float* __restrict__ Pp = P + (size_t)s * (128 * 4096);
  #pragma unroll
  for (int m = 0; m < 4; ++m) {
    const int rbase = 64 * wr + 16 * m + ((lane >> 4) << 2);
    #pragma unroll
    for (int n = 0; n < 4; ++n) {
      const int col = nbase + 64 * wc + 16 * n + (lane & 15);
      #pragma unroll
      for (int r = 0; r < 4; ++r)
        Pp[(size_t)(rbase + r) * 4096 + col] = acc[m][n][r];
    }
  }
}

// ---------------- reduce 8 f32 partials -> fp32 logits [128][2048] ------------
__global__ __launch_bounds__(256) void reduce_linear_kernel(
    const float* __restrict__ P, float* __restrict__ logits)
{
  const int e = blockIdx.x * 1024 + threadIdx.x * 4;
  const int b = e >> 11;
  const int n = e & 2047;
  const size_t off = (size_t)b * 4096 + n;
  float4 sum = *(const float4*)(&P[off]);
  #pragma unroll
  for (int s = 1; s < 8; ++s) {
    float4 v = *(const float4*)(&P[(size_t)s * 524288 + off]);
    sum.x += v.x; sum.y += v.y; sum.z += v.z; sum.w += v.w;
  }
  *(float4*)(&logits[e]) = sum;
}

// ---------------- bias + average + log_softmax ----------------
__global__ __launch_bounds__(256) void logsoftmax_kernel(
    const float* __restrict__ logits, const float* __restrict__ bcls,
    const float* __restrict__ bdist, float* __restrict__ out)
{
  __shared__ float v[1000];
  __shared__ float red[256];
  const int b = blockIdx.x;
  const int tid = threadIdx.x;
  float lmax = -1e30f;
  for (int n = tid; n < 1000; n += 256) {
    float val = 0.5f * (logits[(size_t)b * 2048 + n] + bcls[n]
                      + logits[(size_t)b * 2048 + 1024 + n] + bdist[n]);
    v[n] = val;
    lmax = fmaxf(lmax, val);
  }
  red[tid] = lmax; __syncthreads();
  for (int st = 128; st > 0; st >>= 1) {
    if (tid < st) red[tid] = fmaxf(red[tid], red[tid + st]);
    __syncthreads();
  }
  const float mx = red[0];
  __syncthreads();
  float lsum = 0.f;
  for (int n = tid; n < 1000; n += 256) lsum += expf(v[n] - mx);
  red[tid] = lsum; __syncthreads();
  for (int st = 128; st > 0; st >>= 1) {
    if (tid < st) red[tid] += red[tid + st];
    __syncthreads();
  }
  const float lse = logf(red[0]) + mx;
  for (int n = tid; n < 1000; n += 256) out[(size_t)b * 1000 + n] = v[n] - lse;
}

// ---------------- host ----------------
extern "C" void kernel_launch(void* const* d_in, const int* in_sizes, int n_in,
                              void* d_out, int out_size, void* d_ws, size_t ws_size,
                              hipStream_t stream)
{
  (void)in_sizes; (void)n_in; (void)out_size; (void)ws_size;
  const float* x      = (const float*)d_in[0];
  const float* convw  = (const float*)d_in[1];
  const float* convb  = (const float*)d_in[2];
  const float* wres   = (const float*)d_in[3];
  const float* winp   = (const float*)d_in[4];
  const float* clstok = (const float*)d_in[5];
  const float* dsttok = (const float*)d_in[6];
  const float* wcls   = (const float*)d_in[7];
  const float* bcls   = (const float*)d_in[8];
  const float* wdist  = (const float*)d_in[9];
  const float* bdist  = (const float*)d_in[10];
  float* out = (float*)d_out;

  char* ws = (char*)d_ws;
  unsigned short* U     = (unsigned short*)(ws + 0);           //  4,227,072 (258 steps, tiled)
  unsigned short* A0    = (unsigned short*)(ws + 4227072);     //  1,048,576 (tiled)
  unsigned short* A1    = (unsigned short*)(ws + 5275648);     //  1,048,576 (tiled)
  unsigned short* Hcls  = (unsigned short*)(ws + 6324224);     //  1,048,576 (row-major)
  unsigned short* Hdist = (unsigned short*)(ws + 7372800);     //  1,048,576 (row-major)
  unsigned short* Wcat  = (unsigned short*)(ws + 8421376);     // 16,777,216
  float*          P     = (float*)(ws + 25198592);             // 16,777,216
  float*          logit = (float*)(ws + 41975808);             //  1,048,576
  unsigned int*   cnt   = (unsigned int*)(ws + 43024384);      //  4 KB (producer counters)
  unsigned short* A2    = (unsigned short*)(ws + 25198592);    //  aliases P head (timeline-disjoint)

  hipFuncSetAttribute((const void*)reservoir_persistent,
                      hipFuncAttributeMaxDynamicSharedMemorySize, 110592);

  hipMemsetAsync(A0, 0, 2 * 1048576, stream);                  // A0 + A1 (h0 = 0)
  hipMemsetAsync(cnt, 0, 4096, stream);                        // producer counters

  prep_wc_kernel<<<2048, 256, 0, stream>>>(wcls, wdist, Wcat);
  conv_kernel<<<2048, 256, 0, stream>>>(x, convw, convb, U);
  prep_tok_kernel<<<64, 256, 0, stream>>>(clstok, dsttok, U);

  reservoir_persistent<<<256, 512, 110592, stream>>>(
      wres, U, winp, A0, A1, A2, Hcls, Hdist, cnt);

  gemm_ksplit<<<128, 256, 0, stream>>>(Hcls, Hdist, 8, 4096, Wcat, 4096, P, 16, 512, 512);
  reduce_linear_kernel<<<256, 256, 0, stream>>>(P, logit);
  logsoftmax_kernel<<<128, 256, 0, stream>>>(logit, bcls, bdist, out);
}

// Round 8
// 3206.985 us; speedup vs baseline: 2.5919x; 1.5516x over previous
//
#include <hip/hip_runtime.h>
#include <hip/hip_bf16.h>

#define LSTEPS 256

typedef short  bf16x8_t  __attribute__((ext_vector_type(8)));
typedef float  f32x4_t   __attribute__((ext_vector_type(4)));
typedef unsigned short us4_t __attribute__((ext_vector_type(4)));

static __device__ __forceinline__ unsigned short f2bf(float f) {
  unsigned int u = __float_as_uint(f);
  unsigned int r = (u + 0x7fffu + ((u >> 16) & 1u)) >> 16;
  return (unsigned short)r;
}
static __device__ __forceinline__ float tanh_fast(float x) {
  float e = __expf(2.f * x);
  return 1.f - 2.f / (e + 1.f);
}

// ---------------- prep: Wcat [2048][4096] bf16 ----------------
__global__ __launch_bounds__(256) void prep_wc_kernel(
    const float* __restrict__ wcls, const float* __restrict__ wdist,
    unsigned short* __restrict__ Wcat)
{
  const int row = blockIdx.x;
  const float* src = nullptr;
  if (row < 1000) src = wcls + (size_t)row * 4096;
  else if (row >= 1024 && row < 2024) src = wdist + (size_t)(row - 1024) * 4096;
  unsigned short* dst = Wcat + (size_t)row * 4096;
  #pragma unroll 4
  for (int r = 0; r < 16; ++r) {
    const int c = r * 256 + threadIdx.x;
    dst[c] = src ? f2bf(src[c]) : (unsigned short)0;
  }
}

// ---------------- conv1d front end: U tiled [t][kg][row][8] bf16 ----------------
__global__ __launch_bounds__(256) void conv_kernel(
    const float* __restrict__ x, const float* __restrict__ w,
    const float* __restrict__ bias, unsigned short* __restrict__ U)
{
  __shared__ float wl[192][64];
  const int b  = blockIdx.x >> 4;
  const int tg = blockIdx.x & 15;
  const int tid = threadIdx.x;
  for (int i = tid; i < 64 * 192; i += 256)
    wl[i % 192][i / 192] = w[i];
  __syncthreads();
  const int wv = tid >> 6, p = tid & 63;
  const float* xb = x + (size_t)b * (3 * 8224);
  const float bp = bias[p];
  for (int tt = 0; tt < 4; ++tt) {
    const int t = tg * 16 + wv * 4 + tt;
    float acc = bp;
    const float* xw = xb + t * 32;
    #pragma unroll
    for (int c = 0; c < 3; ++c)
      #pragma unroll 8
      for (int k = 0; k < 64; ++k)
        acc += xw[c * 8224 + k] * wl[c * 64 + k][p];
    U[((size_t)t * 8 + (p >> 3)) * 1024 + (size_t)b * 8 + (p & 7)] = f2bf(acc);
  }
}

// ---------------- token broadcast into U[256], U[257] (tiled) ----------------
__global__ __launch_bounds__(256) void prep_tok_kernel(
    const float* __restrict__ cls, const float* __restrict__ dist,
    unsigned short* __restrict__ U)
{
  const int i = blockIdx.x * 256 + threadIdx.x;   // 16384 total
  const int s = i >> 13, rem = i & 8191;
  const int kg = rem >> 10, e = rem & 7;
  const float* tok = s ? dist : cls;
  U[(size_t)(256 + s) * 8192 + rem] = f2bf(tok[kg * 8 + e]);
}

// ---------------- persistent reservoir: r5 barrier base + consolidated wins --
// 256 WGs x 512 thr. XCD-aware remap (r7-validated, sync-independent):
// xcd = bid&7; bh = xcd>>2; cg = (xcd&3)*32 + bid>>3. All blocks on an XCD
// share one bh half -> post-barrier L2 refill 1.06->0.53 MB/XCD/step.
// Wave w owns K-slice [w*512,+512): W chunks 0..13 in regs (wf[14][2]),
// chunks 14/15 + u-frags in LDS. 12 plain loads in flight (r5 pipeline,
// compiler-tracked waitcnts; no global_load_lds -- r4 showed it non-temporal).
// Pl stride 36 (r7-validated: bank conflicts halved, f32x4 reduce reads).
// SYNC: r5's verbatim 2-level global barrier (8 groups of 32 via lcnt/lgo +
// gcnt round-trip) -- r6/r7 proved decentralized polling regresses.
__global__ __launch_bounds__(512, 2) void reservoir_persistent(
    const float* __restrict__ wres,          // [4096][4096] f32
    const unsigned short* __restrict__ U,    // [258][8 kg][128][8] bf16 tiled
    const float* __restrict__ winp,          // [4096][64] f32
    unsigned short* __restrict__ A0, unsigned short* __restrict__ A1,
    unsigned short* __restrict__ Hcls, unsigned short* __restrict__ Hdist,
    unsigned int* __restrict__ lcnt, unsigned int* __restrict__ gcnt,
    unsigned int* __restrict__ lgo)
{
  extern __shared__ char smem[];
  float* Pl = (float*)smem;                              // [8][64][36] f32 = 73728 B
  unsigned short* Wu = (unsigned short*)(smem + 73728);  // [2 ct][2 w][64][8] = 4096 B
  char* Wl2 = smem + 77824;                              // [8 w][4 frag][64 lane][16B] = 32768 B

  const int bid  = blockIdx.x;
  const int tid  = threadIdx.x;
  const int w    = tid >> 6;
  const int lane = tid & 63;
  const int q    = lane >> 4;
  const int r    = lane & 15;
  const int xcd  = bid & 7;
  const int bh   = xcd >> 2;
  const int cg   = (xcd & 3) * 32 + (bid >> 3);
  const int nbase = cg * 32;
  const int grp  = bid & 7;                  // barrier group = XCD (L2-local adds)
  const int l16  = lane * 16;

  // ---- prologue: wave's W K-slice -> regs (chunks 0..13) / LDS (14,15) ----
  bf16x8_t wf[14][2];
  #pragma unroll
  for (int kk = 0; kk < 16; ++kk)
    #pragma unroll
    for (int ct = 0; ct < 2; ++ct) {
      const float* src = wres + (size_t)(w * 512 + kk * 32 + q * 8) * 4096
                              + nbase + ct * 16 + r;
      bf16x8_t f;
      #pragma unroll
      for (int e = 0; e < 8; ++e) f[e] = (short)f2bf(src[(size_t)e * 4096]);
      if (kk < 14) wf[kk][ct] = f;
      else *(bf16x8_t*)(Wl2 + w * 4096 + ((kk - 14) * 2 + ct) * 1024 + l16) = f;
    }
  if (w < 2) {                               // u-part frags parked in LDS
    #pragma unroll
    for (int ct = 0; ct < 2; ++ct) {
      const float* src = winp + (size_t)(nbase + ct * 16 + r) * 64 + w * 32 + q * 8;
      bf16x8_t f;
      #pragma unroll
      for (int e = 0; e < 8; ++e) f[e] = (short)f2bf(src[e]);
      *(bf16x8_t*)(Wu + ((size_t)(ct * 2 + w) * 64 + lane) * 8) = f;
    }
  }

  // lane's A base in bf16x8 (16B) units: kg = w*64+q (+4/chunk), row = bh*64+r
  const int au = (w * 64 + q) * 128 + bh * 64 + r;
  const int uu = (w * 4 + q) * 128 + bh * 64 + r;   // U slab unit idx (waves 0/1)

  const int erow = tid >> 3;                 // reduce-phase mapping
  const int cb   = (tid & 7) * 4;
  const size_t awoff = ((size_t)(cg * 4 + (cb >> 3)) * 128 + bh * 64 + erow) * 8 + (cb & 7);
  const size_t hoff  = (size_t)(bh * 64 + erow) * 4096 + nbase + cb;

  unsigned int phase = 0;

#define LD(BUF, KK)                                                          \
  { BUF[0] = Ab[au + (KK) * 512];      BUF[1] = Ab[au + (KK) * 512 + 16];    \
    BUF[2] = Ab[au + (KK) * 512 + 32]; BUF[3] = Ab[au + (KK) * 512 + 48]; }

#define MMc(BUF, KK)                                                         \
  { acc[0][0] = __builtin_amdgcn_mfma_f32_16x16x32_bf16(BUF[0], wf[KK][0], acc[0][0], 0, 0, 0); \
    acc[0][1] = __builtin_amdgcn_mfma_f32_16x16x32_bf16(BUF[0], wf[KK][1], acc[0][1], 0, 0, 0); \
    acc[1][0] = __builtin_amdgcn_mfma_f32_16x16x32_bf16(BUF[1], wf[KK][0], acc[1][0], 0, 0, 0); \
    acc[1][1] = __builtin_amdgcn_mfma_f32_16x16x32_bf16(BUF[1], wf[KK][1], acc[1][1], 0, 0, 0); \
    acc[2][0] = __builtin_amdgcn_mfma_f32_16x16x32_bf16(BUF[2], wf[KK][0], acc[2][0], 0, 0, 0); \
    acc[2][1] = __builtin_amdgcn_mfma_f32_16x16x32_bf16(BUF[2], wf[KK][1], acc[2][1], 0, 0, 0); \
    acc[3][0] = __builtin_amdgcn_mfma_f32_16x16x32_bf16(BUF[3], wf[KK][0], acc[3][0], 0, 0, 0); \
    acc[3][1] = __builtin_amdgcn_mfma_f32_16x16x32_bf16(BUF[3], wf[KK][1], acc[3][1], 0, 0, 0); }

#define MMW(BUF, W0, W1)                                                     \
  { acc[0][0] = __builtin_amdgcn_mfma_f32_16x16x32_bf16(BUF[0], W0, acc[0][0], 0, 0, 0); \
    acc[0][1] = __builtin_amdgcn_mfma_f32_16x16x32_bf16(BUF[0], W1, acc[0][1], 0, 0, 0); \
    acc[1][0] = __builtin_amdgcn_mfma_f32_16x16x32_bf16(BUF[1], W0, acc[1][0], 0, 0, 0); \
    acc[1][1] = __builtin_amdgcn_mfma_f32_16x16x32_bf16(BUF[1], W1, acc[1][1], 0, 0, 0); \
    acc[2][0] = __builtin_amdgcn_mfma_f32_16x16x32_bf16(BUF[2], W0, acc[2][0], 0, 0, 0); \
    acc[2][1] = __builtin_amdgcn_mfma_f32_16x16x32_bf16(BUF[2], W1, acc[2][1], 0, 0, 0); \
    acc[3][0] = __builtin_amdgcn_mfma_f32_16x16x32_bf16(BUF[3], W0, acc[3][0], 0, 0, 0); \
    acc[3][1] = __builtin_amdgcn_mfma_f32_16x16x32_bf16(BUF[3], W1, acc[3][1], 0, 0, 0); }

  #pragma unroll 1
  for (int t = 0; t < LSTEPS + 2; ++t) {
    const unsigned short* Arp = (t <= LSTEPS) ? ((t & 1) ? A1 : A0) : A0;
    unsigned short* Awp = ((t + 1) & 1) ? A1 : A0;
    const bf16x8_t* __restrict__ Ab = (const bf16x8_t*)Arp;
    const bf16x8_t* __restrict__ Ub = (const bf16x8_t*)(U + (size_t)t * 8192);

    f32x4_t acc[4][2];
    #pragma unroll
    for (int m = 0; m < 4; ++m) {
      acc[m][0] = (f32x4_t){0.f, 0.f, 0.f, 0.f};
      acc[m][1] = (f32x4_t){0.f, 0.f, 0.f, 0.f};
    }

    bf16x8_t bu[4];
    if (w < 2) {                             // U slab prefetch (independent loads)
      bu[0] = Ub[uu];      bu[1] = Ub[uu + 16];
      bu[2] = Ub[uu + 32]; bu[3] = Ub[uu + 48];
    }

    bf16x8_t b0[4], b1[4], b2[4];
    LD(b0, 0); LD(b1, 1); LD(b2, 2);         // 12 A-loads in flight

    MMc(b0, 0);  LD(b0, 3);
    MMc(b1, 1);  LD(b1, 4);
    MMc(b2, 2);  LD(b2, 5);
    MMc(b0, 3);  LD(b0, 6);
    MMc(b1, 4);  LD(b1, 7);
    MMc(b2, 5);  LD(b2, 8);
    MMc(b0, 6);  LD(b0, 9);
    MMc(b1, 7);  LD(b1, 10);
    MMc(b2, 8);  LD(b2, 11);
    MMc(b0, 9);  LD(b0, 12);
    MMc(b1, 10); LD(b1, 13);
    MMc(b2, 11); LD(b2, 14);
    MMc(b0, 12); LD(b0, 15);
    MMc(b1, 13);
    {                                        // chunks 14/15: W frags from LDS
      const char* wl = Wl2 + w * 4096 + l16;
      bf16x8_t w14a = *(const bf16x8_t*)(wl);
      bf16x8_t w14b = *(const bf16x8_t*)(wl + 1024);
      bf16x8_t w15a = *(const bf16x8_t*)(wl + 2048);
      bf16x8_t w15b = *(const bf16x8_t*)(wl + 3072);
      MMW(b2, w14a, w14b);
      MMW(b0, w15a, w15b);
    }
    if (w < 2) {                             // u half-window
      bf16x8_t wu0 = *(const bf16x8_t*)(Wu + ((size_t)(0 * 2 + w) * 64 + lane) * 8);
      bf16x8_t wu1 = *(const bf16x8_t*)(Wu + ((size_t)(1 * 2 + w) * 64 + lane) * 8);
      MMW(bu, wu0, wu1);
    }

    // ---- cross-wave K reduction through LDS (stride 36: f4-aligned reads) ----
    __syncthreads();
    #pragma unroll
    for (int rt = 0; rt < 4; ++rt)
      #pragma unroll
      for (int ct = 0; ct < 2; ++ct)
        #pragma unroll
        for (int i = 0; i < 4; ++i)
          Pl[(w * 64 + rt * 16 + q * 4 + i) * 36 + ct * 16 + r] = acc[rt][ct][i];
    __syncthreads();

    {
      float s0 = 0.f, s1 = 0.f, s2 = 0.f, s3 = 0.f;
      #pragma unroll
      for (int wv = 0; wv < 8; ++wv) {
        const f32x4_t vv = *(const f32x4_t*)(Pl + (wv * 64 + erow) * 36 + cb);
        s0 += vv[0]; s1 += vv[1]; s2 += vv[2]; s3 += vv[3];
      }
      us4_t o;
      o[0] = f2bf(tanh_fast(s0));
      o[1] = f2bf(tanh_fast(s1));
      o[2] = f2bf(tanh_fast(s2));
      o[3] = f2bf(tanh_fast(s3));
      if (t < LSTEPS) {
        *(us4_t*)(Awp + awoff) = o;          // tiled A cell, 8B store
      } else {
        unsigned short* H = (t == LSTEPS) ? Hcls : Hdist;
        *(us4_t*)(H + hoff) = o;             // row-major H, 8B store
      }
    }

    // ---- grid barrier (verbatim r5 scheme: 8 groups of 32 blocks) ----
    phase += 1;
    __syncthreads();
    if (tid == 0) {
      unsigned int prev = __hip_atomic_fetch_add(&lcnt[grp * 32], 1u,
                            __ATOMIC_RELAXED, __HIP_MEMORY_SCOPE_AGENT);
      if (prev == phase * 32u - 1u) {
        __hip_atomic_fetch_add(gcnt, 1u, __ATOMIC_RELEASE, __HIP_MEMORY_SCOPE_AGENT);
        while (__hip_atomic_load(gcnt, __ATOMIC_RELAXED, __HIP_MEMORY_SCOPE_SYSTEM)
               < phase * 8u)
          __builtin_amdgcn_s_sleep(1);
        (void)__hip_atomic_load(gcnt, __ATOMIC_ACQUIRE, __HIP_MEMORY_SCOPE_AGENT);
        __hip_atomic_store(&lgo[grp * 32], phase,
                           __ATOMIC_RELAXED, __HIP_MEMORY_SCOPE_AGENT);
      } else {
        while (__hip_atomic_load(&lgo[grp * 32], __ATOMIC_RELAXED,
                                 __HIP_MEMORY_SCOPE_SYSTEM) < phase)
          __builtin_amdgcn_s_sleep(1);
      }
    }
    __syncthreads();
  }
#undef LD
#undef MMc
#undef MMW
}

// ---------------- classifier K-split GEMM (f32 partials) ----------
__global__ __launch_bounds__(256) void gemm_ksplit(
    const unsigned short* __restrict__ A0, const unsigned short* __restrict__ A1,
    int nsplit, int lda,
    const unsigned short* __restrict__ BT, int ldb,
    float* __restrict__ P, int ntiles, int klen, int klen_last)
{
  __shared__ unsigned short sA[128 * 64];
  __shared__ unsigned short sB[128 * 64];

  const int bid = blockIdx.x;
  const int nt = bid % ntiles;
  const int s  = bid / ntiles;
  const unsigned short* __restrict__ A = (nt < nsplit) ? A0 : A1;
  const int kb0 = s * klen;
  const int KL  = (s == 7) ? klen_last : klen;
  const int nbase = nt * 128;

  const int tid = threadIdx.x;
  const int w = tid >> 6;
  const int lane = tid & 63;
  const int wr = w >> 1, wc = w & 1;

  f32x4_t acc[4][4];
  #pragma unroll
  for (int m = 0; m < 4; ++m)
    #pragma unroll
    for (int n = 0; n < 4; ++n)
      acc[m][n] = (f32x4_t){0.f, 0.f, 0.f, 0.f};

  const int srow = lane >> 3;
  const int slotL = (lane & 7) ^ srow;

  for (int kb = 0; kb < KL; kb += 64) {
    const int kcol = kb0 + kb + slotL * 8;
    #pragma unroll
    for (int qq = 0; qq < 4; ++qq) {
      const int row = 32 * w + 8 * qq + srow;
      __builtin_amdgcn_global_load_lds(
          (const __attribute__((address_space(1))) void*)(A + (size_t)row * lda + kcol),
          (__attribute__((address_space(3))) void*)(&sA[(32 * w + 8 * qq) * 64]),
          16, 0, 0);
      __builtin_amdgcn_global_load_lds(
          (const __attribute__((address_space(1))) void*)(BT + (size_t)(nbase + row) * ldb + kcol),
          (__attribute__((address_space(3))) void*)(&sB[(32 * w + 8 * qq) * 64]),
          16, 0, 0);
    }
    __syncthreads();

    #pragma unroll
    for (int ksub = 0; ksub < 2; ++ksub) {
      bf16x8_t af[4], bfr[4];
      #pragma unroll
      for (int m = 0; m < 4; ++m) {
        const int row = 64 * wr + 16 * m + (lane & 15);
        const int kslot = (ksub * 4 + (lane >> 4)) ^ (row & 7);
        af[m] = *(const bf16x8_t*)(&sA[row * 64 + kslot * 8]);
      }
      #pragma unroll
      for (int n = 0; n < 4; ++n) {
        const int row = 64 * wc + 16 * n + (lane & 15);
        const int kslot = (ksub * 4 + (lane >> 4)) ^ (row & 7);
        bfr[n] = *(const bf16x8_t*)(&sB[row * 64 + kslot * 8]);
      }
      #pragma unroll
      for (int m = 0; m < 4; ++m)
        #pragma unroll
        for (int n = 0; n < 4; ++n)
          acc[m][n] = __builtin_amdgcn_mfma_f32_16x16x32_bf16(af[m], bfr[n], acc[m][n], 0, 0, 0);
    }
    __syncthreads();
  }

  float* __restrict__ Pp = P + (size_t)s * (128 * 4096);
  #pragma unroll
  for (int m = 0; m < 4; ++m) {
    const int rbase = 64 * wr + 16 * m + ((lane >> 4) << 2);
    #pragma unroll
    for (int n = 0; n < 4; ++n) {
      const int col = nbase + 64 * wc + 16 * n + (lane & 15);
      #pragma unroll
      for (int r = 0; r < 4; ++r)
        Pp[(size_t)(rbase + r) * 4096 + col] = acc[m][n][r];
    }
  }
}

// ---------------- reduce 8 f32 partials -> fp32 logits [128][2048] ------------
__global__ __launch_bounds__(256) void reduce_linear_kernel(
    const float* __restrict__ P, float* __restrict__ logits)
{
  const int e = blockIdx.x * 1024 + threadIdx.x * 4;
  const int b = e >> 11;
  const int n = e & 2047;
  const size_t off = (size_t)b * 4096 + n;
  float4 sum = *(const float4*)(&P[off]);
  #pragma unroll
  for (int s = 1; s < 8; ++s) {
    float4 v = *(const float4*)(&P[(size_t)s * 524288 + off]);
    sum.x += v.x; sum.y += v.y; sum.z += v.z; sum.w += v.w;
  }
  *(float4*)(&logits[e]) = sum;
}

// ---------------- bias + average + log_softmax ----------------
__global__ __launch_bounds__(256) void logsoftmax_kernel(
    const float* __restrict__ logits, const float* __restrict__ bcls,
    const float* __restrict__ bdist, float* __restrict__ out)
{
  __shared__ float v[1000];
  __shared__ float red[256];
  const int b = blockIdx.x;
  const int tid = threadIdx.x;
  float lmax = -1e30f;
  for (int n = tid; n < 1000; n += 256) {
    float val = 0.5f * (logits[(size_t)b * 2048 + n] + bcls[n]
                      + logits[(size_t)b * 2048 + 1024 + n] + bdist[n]);
    v[n] = val;
    lmax = fmaxf(lmax, val);
  }
  red[tid] = lmax; __syncthreads();
  for (int st = 128; st > 0; st >>= 1) {
    if (tid < st) red[tid] = fmaxf(red[tid], red[tid + st]);
    __syncthreads();
  }
  const float mx = red[0];
  __syncthreads();
  float lsum = 0.f;
  for (int n = tid; n < 1000; n += 256) lsum += expf(v[n] - mx);
  red[tid] = lsum; __syncthreads();
  for (int st = 128; st > 0; st >>= 1) {
    if (tid < st) red[tid] += red[tid + st];
    __syncthreads();
  }
  const float lse = logf(red[0]) + mx;
  for (int n = tid; n < 1000; n += 256) out[(size_t)b * 1000 + n] = v[n] - lse;
}

// ---------------- host ----------------
extern "C" void kernel_launch(void* const* d_in, const int* in_sizes, int n_in,
                              void* d_out, int out_size, void* d_ws, size_t ws_size,
                              hipStream_t stream)
{
  (void)in_sizes; (void)n_in; (void)out_size; (void)ws_size;
  const float* x      = (const float*)d_in[0];
  const float* convw  = (const float*)d_in[1];
  const float* convb  = (const float*)d_in[2];
  const float* wres   = (const float*)d_in[3];
  const float* winp   = (const float*)d_in[4];
  const float* clstok = (const float*)d_in[5];
  const float* dsttok = (const float*)d_in[6];
  const float* wcls   = (const float*)d_in[7];
  const float* bcls   = (const float*)d_in[8];
  const float* wdist  = (const float*)d_in[9];
  const float* bdist  = (const float*)d_in[10];
  float* out = (float*)d_out;

  char* ws = (char*)d_ws;
  unsigned short* U     = (unsigned short*)(ws + 0);           //  4,227,072 (258 steps, tiled)
  unsigned short* A0    = (unsigned short*)(ws + 4227072);     //  1,048,576 (tiled)
  unsigned short* A1    = (unsigned short*)(ws + 5275648);     //  1,048,576 (tiled)
  unsigned short* Hcls  = (unsigned short*)(ws + 6324224);     //  1,048,576 (row-major)
  unsigned short* Hdist = (unsigned short*)(ws + 7372800);     //  1,048,576 (row-major)
  unsigned short* Wcat  = (unsigned short*)(ws + 8421376);     // 16,777,216
  float*          P     = (float*)(ws + 25198592);             // 16,777,216
  float*          logit = (float*)(ws + 41975808);             //  1,048,576
  unsigned int*   lcnt  = (unsigned int*)(ws + 43024384);      //  1 KB
  unsigned int*   lgo   = (unsigned int*)(ws + 43025408);      //  1 KB
  unsigned int*   gcnt  = (unsigned int*)(ws + 43026432);      //  1 line

  hipFuncSetAttribute((const void*)reservoir_persistent,
                      hipFuncAttributeMaxDynamicSharedMemorySize, 110592);

  hipMemsetAsync(A0, 0, 2 * 1048576, stream);                  // A0 + A1 (h0 = 0)
  hipMemsetAsync(lcnt, 0, 4096, stream);                       // lcnt+lgo+gcnt

  prep_wc_kernel<<<2048, 256, 0, stream>>>(wcls, wdist, Wcat);
  conv_kernel<<<2048, 256, 0, stream>>>(x, convw, convb, U);
  prep_tok_kernel<<<64, 256, 0, stream>>>(clstok, dsttok, U);

  reservoir_persistent<<<256, 512, 110592, stream>>>(
      wres, U, winp, A0, A1, Hcls, Hdist, lcnt, gcnt, lgo);

  gemm_ksplit<<<128, 256, 0, stream>>>(Hcls, Hdist, 8, 4096, Wcat, 4096, P, 16, 512, 512);
  reduce_linear_kernel<<<256, 256, 0, stream>>>(P, logit);
  logsoftmax_kernel<<<128, 256, 0, stream>>>(logit, bcls, bdist, out);
}

// Round 9
// 2908.194 us; speedup vs baseline: 2.8582x; 1.1027x over previous
//
#include <hip/hip_runtime.h>
#include <hip/hip_bf16.h>

#define LSTEPS 256

typedef short  bf16x8_t  __attribute__((ext_vector_type(8)));
typedef float  f32x4_t   __attribute__((ext_vector_type(4)));
typedef unsigned short us4_t __attribute__((ext_vector_type(4)));

static __device__ __forceinline__ unsigned short f2bf(float f) {
  unsigned int u = __float_as_uint(f);
  unsigned int r = (u + 0x7fffu + ((u >> 16) & 1u)) >> 16;
  return (unsigned short)r;
}
static __device__ __forceinline__ float tanh_fast(float x) {
  float e = __expf(2.f * x);
  return 1.f - 2.f / (e + 1.f);
}

// ---------------- prep: Wcat [2048][4096] bf16 ----------------
__global__ __launch_bounds__(256) void prep_wc_kernel(
    const float* __restrict__ wcls, const float* __restrict__ wdist,
    unsigned short* __restrict__ Wcat)
{
  const int row = blockIdx.x;
  const float* src = nullptr;
  if (row < 1000) src = wcls + (size_t)row * 4096;
  else if (row >= 1024 && row < 2024) src = wdist + (size_t)(row - 1024) * 4096;
  unsigned short* dst = Wcat + (size_t)row * 4096;
  #pragma unroll 4
  for (int r = 0; r < 16; ++r) {
    const int c = r * 256 + threadIdx.x;
    dst[c] = src ? f2bf(src[c]) : (unsigned short)0;
  }
}

// ---------------- conv1d front end: U tiled [t][kg][row][8] bf16 ----------------
__global__ __launch_bounds__(256) void conv_kernel(
    const float* __restrict__ x, const float* __restrict__ w,
    const float* __restrict__ bias, unsigned short* __restrict__ U)
{
  __shared__ float wl[192][64];
  const int b  = blockIdx.x >> 4;
  const int tg = blockIdx.x & 15;
  const int tid = threadIdx.x;
  for (int i = tid; i < 64 * 192; i += 256)
    wl[i % 192][i / 192] = w[i];
  __syncthreads();
  const int wv = tid >> 6, p = tid & 63;
  const float* xb = x + (size_t)b * (3 * 8224);
  const float bp = bias[p];
  for (int tt = 0; tt < 4; ++tt) {
    const int t = tg * 16 + wv * 4 + tt;
    float acc = bp;
    const float* xw = xb + t * 32;
    #pragma unroll
    for (int c = 0; c < 3; ++c)
      #pragma unroll 8
      for (int k = 0; k < 64; ++k)
        acc += xw[c * 8224 + k] * wl[c * 64 + k][p];
    U[((size_t)t * 8 + (p >> 3)) * 1024 + (size_t)b * 8 + (p & 7)] = f2bf(acc);
  }
}

// ---------------- token broadcast into U[256], U[257] (tiled) ----------------
__global__ __launch_bounds__(256) void prep_tok_kernel(
    const float* __restrict__ cls, const float* __restrict__ dist,
    unsigned short* __restrict__ U)
{
  const int i = blockIdx.x * 256 + threadIdx.x;   // 16384 total
  const int s = i >> 13, rem = i & 8191;
  const int kg = rem >> 10, e = rem & 7;
  const float* tok = s ? dist : cls;
  U[(size_t)(256 + s) * 8192 + rem] = f2bf(tok[kg * 8 + e]);
}

// ---------------- persistent reservoir: W register-resident, batch-split ------
// 256 WGs x 512 thr. cg = bid>>1 owns cols [cg*32,+32); bh = bid&1 owns batch
// rows [bh*64,+64). Wave w owns K-slice [w*512,+512): W chunks 0..13 in
// VGPRs/AGPRs (wf[14][2] = 112 regs), chunks 14/15 parked in LDS (Wl2, 32 KB,
// same-thread write->read, conflict-free 16B/lane) to free 16 arch VGPRs for
// a THIRD staging buffer b2 -> 12 plain loads in flight (r0-proven depth,
// 79 GB/s/CU) on the halved 0.53 MB/CU/step footprint.
// Loads are plain C: compiler-tracked waitcnts (correct even under spill).
// NO global_load_lds (r4: non-temporal reads, 2.4x slower). Stride-33 Pl
// reduce (r8 falsified the stride-36 f32x4 variant: 8-way read conflicts).
// bh = bid&1 with round-robin dispatch already gives per-XCD bh locality.
// SYNC: proven 2-level global barrier (r6/r7 falsified decentralized polling).
// BEST VERIFIED CONFIG (r5): 2923 us total.
__global__ __launch_bounds__(512, 2) void reservoir_persistent(
    const float* __restrict__ wres,          // [4096][4096] f32
    const unsigned short* __restrict__ U,    // [258][8 kg][128][8] bf16 tiled
    const float* __restrict__ winp,          // [4096][64] f32
    unsigned short* __restrict__ A0, unsigned short* __restrict__ A1,
    unsigned short* __restrict__ Hcls, unsigned short* __restrict__ Hdist,
    unsigned int* __restrict__ lcnt, unsigned int* __restrict__ gcnt,
    unsigned int* __restrict__ lgo)
{
  extern __shared__ char smem[];
  float* Pl = (float*)smem;                              // [8][64][33] f32 = 67584 B
  unsigned short* Wu = (unsigned short*)(smem + 67584);  // [2 ct][2 w][64][8] = 4096 B
  char* Wl2 = smem + 71680;                              // [8 w][4 frag][64 lane][16B] = 32768 B

  const int bid  = blockIdx.x;
  const int tid  = threadIdx.x;
  const int w    = tid >> 6;
  const int lane = tid & 63;
  const int q    = lane >> 4;
  const int r    = lane & 15;
  const int cg   = bid >> 1;
  const int bh   = bid & 1;
  const int nbase = cg * 32;
  const int grp  = bid & 7;
  const int l16  = lane * 16;

  // ---- prologue: wave's W K-slice -> regs (chunks 0..13) / LDS (14,15) ----
  bf16x8_t wf[14][2];
  #pragma unroll
  for (int kk = 0; kk < 16; ++kk)
    #pragma unroll
    for (int ct = 0; ct < 2; ++ct) {
      const float* src = wres + (size_t)(w * 512 + kk * 32 + q * 8) * 4096
                              + nbase + ct * 16 + r;
      bf16x8_t f;
      #pragma unroll
      for (int e = 0; e < 8; ++e) f[e] = (short)f2bf(src[(size_t)e * 4096]);
      if (kk < 14) wf[kk][ct] = f;
      else *(bf16x8_t*)(Wl2 + w * 4096 + ((kk - 14) * 2 + ct) * 1024 + l16) = f;
    }
  if (w < 2) {                               // u-part frags parked in LDS
    #pragma unroll
    for (int ct = 0; ct < 2; ++ct) {
      const float* src = winp + (size_t)(nbase + ct * 16 + r) * 64 + w * 32 + q * 8;
      bf16x8_t f;
      #pragma unroll
      for (int e = 0; e < 8; ++e) f[e] = (short)f2bf(src[e]);
      *(bf16x8_t*)(Wu + ((size_t)(ct * 2 + w) * 64 + lane) * 8) = f;
    }
  }

  // lane's A base in bf16x8 (16B) units: kg = w*64+q (+4/chunk), row = bh*64+r
  const int au = (w * 64 + q) * 128 + bh * 64 + r;
  const int uu = (w * 4 + q) * 128 + bh * 64 + r;   // U slab unit idx (waves 0/1)

  const int erow = tid >> 3;                 // reduce-phase mapping
  const int cb   = (tid & 7) * 4;
  const size_t awoff = ((size_t)(cg * 4 + (cb >> 3)) * 128 + bh * 64 + erow) * 8 + (cb & 7);
  const size_t hoff  = (size_t)(bh * 64 + erow) * 4096 + nbase + cb;

  unsigned int phase = 0;

#define LD(BUF, KK)                                                          \
  { BUF[0] = Ab[au + (KK) * 512];      BUF[1] = Ab[au + (KK) * 512 + 16];    \
    BUF[2] = Ab[au + (KK) * 512 + 32]; BUF[3] = Ab[au + (KK) * 512 + 48]; }

#define MMc(BUF, KK)                                                         \
  { acc[0][0] = __builtin_amdgcn_mfma_f32_16x16x32_bf16(BUF[0], wf[KK][0], acc[0][0], 0, 0, 0); \
    acc[0][1] = __builtin_amdgcn_mfma_f32_16x16x32_bf16(BUF[0], wf[KK][1], acc[0][1], 0, 0, 0); \
    acc[1][0] = __builtin_amdgcn_mfma_f32_16x16x32_bf16(BUF[1], wf[KK][0], acc[1][0], 0, 0, 0); \
    acc[1][1] = __builtin_amdgcn_mfma_f32_16x16x32_bf16(BUF[1], wf[KK][1], acc[1][1], 0, 0, 0); \
    acc[2][0] = __builtin_amdgcn_mfma_f32_16x16x32_bf16(BUF[2], wf[KK][0], acc[2][0], 0, 0, 0); \
    acc[2][1] = __builtin_amdgcn_mfma_f32_16x16x32_bf16(BUF[2], wf[KK][1], acc[2][1], 0, 0, 0); \
    acc[3][0] = __builtin_amdgcn_mfma_f32_16x16x32_bf16(BUF[3], wf[KK][0], acc[3][0], 0, 0, 0); \
    acc[3][1] = __builtin_amdgcn_mfma_f32_16x16x32_bf16(BUF[3], wf[KK][1], acc[3][1], 0, 0, 0); }

#define MMW(BUF, W0, W1)                                                     \
  { acc[0][0] = __builtin_amdgcn_mfma_f32_16x16x32_bf16(BUF[0], W0, acc[0][0], 0, 0, 0); \
    acc[0][1] = __builtin_amdgcn_mfma_f32_16x16x32_bf16(BUF[0], W1, acc[0][1], 0, 0, 0); \
    acc[1][0] = __builtin_amdgcn_mfma_f32_16x16x32_bf16(BUF[1], W0, acc[1][0], 0, 0, 0); \
    acc[1][1] = __builtin_amdgcn_mfma_f32_16x16x32_bf16(BUF[1], W1, acc[1][1], 0, 0, 0); \
    acc[2][0] = __builtin_amdgcn_mfma_f32_16x16x32_bf16(BUF[2], W0, acc[2][0], 0, 0, 0); \
    acc[2][1] = __builtin_amdgcn_mfma_f32_16x16x32_bf16(BUF[2], W1, acc[2][1], 0, 0, 0); \
    acc[3][0] = __builtin_amdgcn_mfma_f32_16x16x32_bf16(BUF[3], W0, acc[3][0], 0, 0, 0); \
    acc[3][1] = __builtin_amdgcn_mfma_f32_16x16x32_bf16(BUF[3], W1, acc[3][1], 0, 0, 0); }

  #pragma unroll 1
  for (int t = 0; t < LSTEPS + 2; ++t) {
    const unsigned short* Arp = (t <= LSTEPS) ? ((t & 1) ? A1 : A0) : A0;
    unsigned short* Awp = ((t + 1) & 1) ? A1 : A0;
    const bf16x8_t* __restrict__ Ab = (const bf16x8_t*)Arp;
    const bf16x8_t* __restrict__ Ub = (const bf16x8_t*)(U + (size_t)t * 8192);

    f32x4_t acc[4][2];
    #pragma unroll
    for (int m = 0; m < 4; ++m) {
      acc[m][0] = (f32x4_t){0.f, 0.f, 0.f, 0.f};
      acc[m][1] = (f32x4_t){0.f, 0.f, 0.f, 0.f};
    }

    bf16x8_t b0[4], b1[4], b2[4];
    LD(b0, 0); LD(b1, 1); LD(b2, 2);         // 12 loads in flight

    MMc(b0, 0);  LD(b0, 3);
    MMc(b1, 1);  LD(b1, 4);
    MMc(b2, 2);  LD(b2, 5);
    MMc(b0, 3);  LD(b0, 6);
    MMc(b1, 4);  LD(b1, 7);
    MMc(b2, 5);  LD(b2, 8);
    MMc(b0, 6);  LD(b0, 9);
    MMc(b1, 7);  LD(b1, 10);
    MMc(b2, 8);  LD(b2, 11);
    MMc(b0, 9);  LD(b0, 12);
    MMc(b1, 10); LD(b1, 13);
    MMc(b2, 11); LD(b2, 14);
    MMc(b0, 12); LD(b0, 15);

    bf16x8_t bu[4];
    if (w < 2) {                             // U slab loads (read-only, no barrier dep)
      bu[0] = Ub[uu];      bu[1] = Ub[uu + 16];
      bu[2] = Ub[uu + 32]; bu[3] = Ub[uu + 48];
    }
    MMc(b1, 13);
    {                                        // chunks 14/15: W frags from LDS
      const char* wl = Wl2 + w * 4096 + l16;
      bf16x8_t w14a = *(const bf16x8_t*)(wl);
      bf16x8_t w14b = *(const bf16x8_t*)(wl + 1024);
      bf16x8_t w15a = *(const bf16x8_t*)(wl + 2048);
      bf16x8_t w15b = *(const bf16x8_t*)(wl + 3072);
      MMW(b2, w14a, w14b);
      MMW(b0, w15a, w15b);
    }
    if (w < 2) {                             // u half-window
      bf16x8_t wu0 = *(const bf16x8_t*)(Wu + ((size_t)(0 * 2 + w) * 64 + lane) * 8);
      bf16x8_t wu1 = *(const bf16x8_t*)(Wu + ((size_t)(1 * 2 + w) * 64 + lane) * 8);
      MMW(bu, wu0, wu1);
    }

    // ---- cross-wave K reduction through LDS ----
    __syncthreads();
    #pragma unroll
    for (int rt = 0; rt < 4; ++rt)
      #pragma unroll
      for (int ct = 0; ct < 2; ++ct)
        #pragma unroll
        for (int i = 0; i < 4; ++i)
          Pl[(w * 64 + rt * 16 + q * 4 + i) * 33 + ct * 16 + r] = acc[rt][ct][i];
    __syncthreads();

    {
      float s0 = 0.f, s1 = 0.f, s2 = 0.f, s3 = 0.f;
      #pragma unroll
      for (int wv = 0; wv < 8; ++wv) {
        const float* p = Pl + (wv * 64 + erow) * 33 + cb;
        s0 += p[0]; s1 += p[1]; s2 += p[2]; s3 += p[3];
      }
      us4_t o;
      o[0] = f2bf(tanh_fast(s0));
      o[1] = f2bf(tanh_fast(s1));
      o[2] = f2bf(tanh_fast(s2));
      o[3] = f2bf(tanh_fast(s3));
      if (t < LSTEPS) {
        *(us4_t*)(Awp + awoff) = o;          // tiled A cell, 8B store
      } else {
        unsigned short* H = (t == LSTEPS) ? Hcls : Hdist;
        *(us4_t*)(H + hoff) = o;             // row-major H, 8B store
      }
    }

    // ---- grid barrier (verbatim scheme: 8 groups of 32 blocks) ----
    phase += 1;
    __syncthreads();
    if (tid == 0) {
      unsigned int prev = __hip_atomic_fetch_add(&lcnt[grp * 32], 1u,
                            __ATOMIC_RELAXED, __HIP_MEMORY_SCOPE_AGENT);
      if (prev == phase * 32u - 1u) {
        __hip_atomic_fetch_add(gcnt, 1u, __ATOMIC_RELEASE, __HIP_MEMORY_SCOPE_AGENT);
        while (__hip_atomic_load(gcnt, __ATOMIC_RELAXED, __HIP_MEMORY_SCOPE_SYSTEM)
               < phase * 8u)
          __builtin_amdgcn_s_sleep(1);
        (void)__hip_atomic_load(gcnt, __ATOMIC_ACQUIRE, __HIP_MEMORY_SCOPE_AGENT);
        __hip_atomic_store(&lgo[grp * 32], phase,
                           __ATOMIC_RELAXED, __HIP_MEMORY_SCOPE_AGENT);
      } else {
        while (__hip_atomic_load(&lgo[grp * 32], __ATOMIC_RELAXED,
                                 __HIP_MEMORY_SCOPE_SYSTEM) < phase)
          __builtin_amdgcn_s_sleep(1);
      }
    }
    __syncthreads();
  }
#undef LD
#undef MMc
#undef MMW
}

// ---------------- classifier K-split GEMM (f32 partials) ----------
__global__ __launch_bounds__(256) void gemm_ksplit(
    const unsigned short* __restrict__ A0, const unsigned short* __restrict__ A1,
    int nsplit, int lda,
    const unsigned short* __restrict__ BT, int ldb,
    float* __restrict__ P, int ntiles, int klen, int klen_last)
{
  __shared__ unsigned short sA[128 * 64];
  __shared__ unsigned short sB[128 * 64];

  const int bid = blockIdx.x;
  const int nt = bid % ntiles;
  const int s  = bid / ntiles;
  const unsigned short* __restrict__ A = (nt < nsplit) ? A0 : A1;
  const int kb0 = s * klen;
  const int KL  = (s == 7) ? klen_last : klen;
  const int nbase = nt * 128;

  const int tid = threadIdx.x;
  const int w = tid >> 6;
  const int lane = tid & 63;
  const int wr = w >> 1, wc = w & 1;

  f32x4_t acc[4][4];
  #pragma unroll
  for (int m = 0; m < 4; ++m)
    #pragma unroll
    for (int n = 0; n < 4; ++n)
      acc[m][n] = (f32x4_t){0.f, 0.f, 0.f, 0.f};

  const int srow = lane >> 3;
  const int slotL = (lane & 7) ^ srow;

  for (int kb = 0; kb < KL; kb += 64) {
    const int kcol = kb0 + kb + slotL * 8;
    #pragma unroll
    for (int qq = 0; qq < 4; ++qq) {
      const int row = 32 * w + 8 * qq + srow;
      __builtin_amdgcn_global_load_lds(
          (const __attribute__((address_space(1))) void*)(A + (size_t)row * lda + kcol),
          (__attribute__((address_space(3))) void*)(&sA[(32 * w + 8 * qq) * 64]),
          16, 0, 0);
      __builtin_amdgcn_global_load_lds(
          (const __attribute__((address_space(1))) void*)(BT + (size_t)(nbase + row) * ldb + kcol),
          (__attribute__((address_space(3))) void*)(&sB[(32 * w + 8 * qq) * 64]),
          16, 0, 0);
    }
    __syncthreads();

    #pragma unroll
    for (int ksub = 0; ksub < 2; ++ksub) {
      bf16x8_t af[4], bfr[4];
      #pragma unroll
      for (int m = 0; m < 4; ++m) {
        const int row = 64 * wr + 16 * m + (lane & 15);
        const int kslot = (ksub * 4 + (lane >> 4)) ^ (row & 7);
        af[m] = *(const bf16x8_t*)(&sA[row * 64 + kslot * 8]);
      }
      #pragma unroll
      for (int n = 0; n < 4; ++n) {
        const int row = 64 * wc + 16 * n + (lane & 15);
        const int kslot = (ksub * 4 + (lane >> 4)) ^ (row & 7);
        bfr[n] = *(const bf16x8_t*)(&sB[row * 64 + kslot * 8]);
      }
      #pragma unroll
      for (int m = 0; m < 4; ++m)
        #pragma unroll
        for (int n = 0; n < 4; ++n)
          acc[m][n] = __builtin_amdgcn_mfma_f32_16x16x32_bf16(af[m], bfr[n], acc[m][n], 0, 0, 0);
    }
    __syncthreads();
  }

  float* __restrict__ Pp = P + (size_t)s * (128 * 4096);
  #pragma unroll
  for (int m = 0; m < 4; ++m) {
    const int rbase = 64 * wr + 16 * m + ((lane >> 4) << 2);
    #pragma unroll
    for (int n = 0; n < 4; ++n) {
      const int col = nbase + 64 * wc + 16 * n + (lane & 15);
      #pragma unroll
      for (int r = 0; r < 4; ++r)
        Pp[(size_t)(rbase + r) * 4096 + col] = acc[m][n][r];
    }
  }
}

// ---------------- reduce 8 f32 partials -> fp32 logits [128][2048] ------------
__global__ __launch_bounds__(256) void reduce_linear_kernel(
    const float* __restrict__ P, float* __restrict__ logits)
{
  const int e = blockIdx.x * 1024 + threadIdx.x * 4;
  const int b = e >> 11;
  const int n = e & 2047;
  const size_t off = (size_t)b * 4096 + n;
  float4 sum = *(const float4*)(&P[off]);
  #pragma unroll
  for (int s = 1; s < 8; ++s) {
    float4 v = *(const float4*)(&P[(size_t)s * 524288 + off]);
    sum.x += v.x; sum.y += v.y; sum.z += v.z; sum.w += v.w;
  }
  *(float4*)(&logits[e]) = sum;
}

// ---------------- bias + average + log_softmax ----------------
__global__ __launch_bounds__(256) void logsoftmax_kernel(
    const float* __restrict__ logits, const float* __restrict__ bcls,
    const float* __restrict__ bdist, float* __restrict__ out)
{
  __shared__ float v[1000];
  __shared__ float red[256];
  const int b = blockIdx.x;
  const int tid = threadIdx.x;
  float lmax = -1e30f;
  for (int n = tid; n < 1000; n += 256) {
    float val = 0.5f * (logits[(size_t)b * 2048 + n] + bcls[n]
                      + logits[(size_t)b * 2048 + 1024 + n] + bdist[n]);
    v[n] = val;
    lmax = fmaxf(lmax, val);
  }
  red[tid] = lmax; __syncthreads();
  for (int st = 128; st > 0; st >>= 1) {
    if (tid < st) red[tid] = fmaxf(red[tid], red[tid + st]);
    __syncthreads();
  }
  const float mx = red[0];
  __syncthreads();
  float lsum = 0.f;
  for (int n = tid; n < 1000; n += 256) lsum += expf(v[n] - mx);
  red[tid] = lsum; __syncthreads();
  for (int st = 128; st > 0; st >>= 1) {
    if (tid < st) red[tid] += red[tid + st];
    __syncthreads();
  }
  const float lse = logf(red[0]) + mx;
  for (int n = tid; n < 1000; n += 256) out[(size_t)b * 1000 + n] = v[n] - lse;
}

// ---------------- host ----------------
extern "C" void kernel_launch(void* const* d_in, const int* in_sizes, int n_in,
                              void* d_out, int out_size, void* d_ws, size_t ws_size,
                              hipStream_t stream)
{
  (void)in_sizes; (void)n_in; (void)out_size; (void)ws_size;
  const float* x      = (const float*)d_in[0];
  const float* convw  = (const float*)d_in[1];
  const float* convb  = (const float*)d_in[2];
  const float* wres   = (const float*)d_in[3];
  const float* winp   = (const float*)d_in[4];
  const float* clstok = (const float*)d_in[5];
  const float* dsttok = (const float*)d_in[6];
  const float* wcls   = (const float*)d_in[7];
  const float* bcls   = (const float*)d_in[8];
  const float* wdist  = (const float*)d_in[9];
  const float* bdist  = (const float*)d_in[10];
  float* out = (float*)d_out;

  char* ws = (char*)d_ws;
  unsigned short* U     = (unsigned short*)(ws + 0);           //  4,227,072 (258 steps, tiled)
  unsigned short* A0    = (unsigned short*)(ws + 4227072);     //  1,048,576 (tiled)
  unsigned short* A1    = (unsigned short*)(ws + 5275648);     //  1,048,576 (tiled)
  unsigned short* Hcls  = (unsigned short*)(ws + 6324224);     //  1,048,576 (row-major)
  unsigned short* Hdist = (unsigned short*)(ws + 7372800);     //  1,048,576 (row-major)
  unsigned short* Wcat  = (unsigned short*)(ws + 8421376);     // 16,777,216
  float*          P     = (float*)(ws + 25198592);             // 16,777,216
  float*          logit = (float*)(ws + 41975808);             //  1,048,576
  unsigned int*   lcnt  = (unsigned int*)(ws + 43024384);      //  1 KB
  unsigned int*   lgo   = (unsigned int*)(ws + 43025408);      //  1 KB
  unsigned int*   gcnt  = (unsigned int*)(ws + 43026432);      //  1 line

  hipFuncSetAttribute((const void*)reservoir_persistent,
                      hipFuncAttributeMaxDynamicSharedMemorySize, 104448);

  hipMemsetAsync(A0, 0, 2 * 1048576, stream);                  // A0 + A1 (h0 = 0)
  hipMemsetAsync(lcnt, 0, 4096, stream);                       // lcnt+lgo+gcnt

  prep_wc_kernel<<<2048, 256, 0, stream>>>(wcls, wdist, Wcat);
  conv_kernel<<<2048, 256, 0, stream>>>(x, convw, convb, U);
  prep_tok_kernel<<<64, 256, 0, stream>>>(clstok, dsttok, U);

  reservoir_persistent<<<256, 512, 104448, stream>>>(
      wres, U, winp, A0, A1, Hcls, Hdist, lcnt, gcnt, lgo);

  gemm_ksplit<<<128, 256, 0, stream>>>(Hcls, Hdist, 8, 4096, Wcat, 4096, P, 16, 512, 512);
  reduce_linear_kernel<<<256, 256, 0, stream>>>(P, logit);
  logsoftmax_kernel<<<128, 256, 0, stream>>>(logit, bcls, bdist, out);
}